// Round 3
// baseline (1222.435 us; speedup 1.0000x reference)
//
#include <hip/hip_runtime.h>

#define NN 50000
#define FF 300
#define DD 128
#define HH 4
#define CC 32
#define EE 640000
#define RR 200
#define LL 2

typedef unsigned short u16;
typedef unsigned int u32;

__device__ __forceinline__ float bf2f(u16 u) {
    union { u32 i; float f; } v; v.i = ((u32)u) << 16; return v.f;
}
__device__ __forceinline__ u16 f2bf(float f) {
    u32 u = __float_as_uint(f);
    u32 r = (u >> 16) & 1u;
    u += 0x7fffu + r;
    return (u16)(u >> 16);
}
// monotone float<->uint mapping so unsigned atomicMax works on signed floats.
// flipped value of any finite float is > 0, so memset-0 is the max-identity.
__device__ __forceinline__ u32 flipf(float f) {
    u32 u = __float_as_uint(f);
    return (u & 0x80000000u) ? ~u : (u | 0x80000000u);
}
__device__ __forceinline__ float unflipf(u32 u) {
    u = (u & 0x80000000u) ? (u & 0x7fffffffu) : ~u;
    return __uint_as_float(u);
}

// ---------------- relation projection: erel[l*RR+r][d] = rel_emb[r,:] @ w_e[l][:,d]
__global__ __launch_bounds__(128)
void relproj_kernel(const float* __restrict__ rel_emb,
                    const float* __restrict__ w_e,
                    float* __restrict__ erel)
{
    int lr = blockIdx.x;            // l*RR + r
    int l = lr / RR, r = lr - l * RR;
    int d = threadIdx.x;
    __shared__ float rv[DD];
    rv[d] = rel_emb[r * DD + d];
    __syncthreads();
    const float* W = w_e + (size_t)l * DD * DD;
    float acc = 0.f;
    #pragma unroll 8
    for (int k = 0; k < DD; k++) acc += rv[k] * W[k * DD + d];
    erel[(size_t)lr * DD + d] = acc;
}

// ---------------- tiled GEMM: C[M,128] = A[M,K] @ B[K,128] + bvec  (all fp32 in)
// A fp32 (optional row indirection). Output fp32 or bf16 (internal layout choice).
#define TILE_M 64
#define TILE_K 16
template<bool OUTBF16>
__global__ __launch_bounds__(256)
void gemm128_kernel(const float* __restrict__ A, const int* __restrict__ rowidx,
                    int lda, const float* __restrict__ B,
                    const float* __restrict__ bvec,
                    void* __restrict__ C_, int M, int K)
{
    __shared__ float As[TILE_K][TILE_M + 4];
    __shared__ float Bs[TILE_K][DD];
    __shared__ int rmap[TILE_M];

    int tid = threadIdx.x;
    int m0 = blockIdx.x * TILE_M;
    if (tid < TILE_M) {
        int r = m0 + tid;
        rmap[tid] = (r < M) ? (rowidx ? rowidx[r] : r) : 0;
    }
    __syncthreads();

    int tx = tid & 31;          // cols tx*4 .. +3
    int ty = tid >> 5;          // rows ty*8 .. +7
    float acc[8][4];
    #pragma unroll
    for (int i = 0; i < 8; i++)
        #pragma unroll
        for (int j = 0; j < 4; j++) acc[i][j] = 0.f;

    int arow = tid >> 2;            // 0..63
    int akq  = (tid & 3) * 4;       // 0,4,8,12
    int brow = tid >> 4;            // 0..15
    int bc   = (tid & 15) * 8;      // 0..120

    for (int kk = 0; kk < K; kk += TILE_K) {
        {
            int rid = rmap[arow];
            #pragma unroll
            for (int j = 0; j < 4; j++) {
                int k = kk + akq + j;
                As[akq + j][arow] = (k < K) ? A[(size_t)rid * lda + k] : 0.f;
            }
        }
        {
            int k = kk + brow;
            #pragma unroll
            for (int j = 0; j < 8; j++)
                Bs[brow][bc + j] = (k < K) ? B[(size_t)k * DD + bc + j] : 0.f;
        }
        __syncthreads();
        #pragma unroll
        for (int k = 0; k < TILE_K; k++) {
            float4 a0 = *(const float4*)&As[k][ty * 8];
            float4 a1 = *(const float4*)&As[k][ty * 8 + 4];
            float4 bq = *(const float4*)&Bs[k][tx * 4];
            float a[8] = {a0.x, a0.y, a0.z, a0.w, a1.x, a1.y, a1.z, a1.w};
            float b[4] = {bq.x, bq.y, bq.z, bq.w};
            #pragma unroll
            for (int i = 0; i < 8; i++)
                #pragma unroll
                for (int j = 0; j < 4; j++) acc[i][j] += a[i] * b[j];
        }
        __syncthreads();
    }

    float bv[4];
    #pragma unroll
    for (int j = 0; j < 4; j++) bv[j] = bvec ? bvec[tx * 4 + j] : 0.f;
    #pragma unroll
    for (int i = 0; i < 8; i++) {
        int r = m0 + ty * 8 + i;
        if (r < M) {
            float o0 = acc[i][0] + bv[0], o1 = acc[i][1] + bv[1];
            float o2 = acc[i][2] + bv[2], o3 = acc[i][3] + bv[3];
            if (OUTBF16) {
                union { u16 h[4]; unsigned long long v; } p;
                p.h[0] = f2bf(o0); p.h[1] = f2bf(o1); p.h[2] = f2bf(o2); p.h[3] = f2bf(o3);
                *(unsigned long long*)((u16*)C_ + (size_t)r * DD + tx * 4) = p.v;
            } else {
                *(float4*)((float*)C_ + (size_t)r * DD + tx * 4) =
                    make_float4(o0, o1, o2, o3);
            }
        }
    }
}

// ---------------- per-(edge,head) logits + segment max
__global__ __launch_bounds__(256)
void edge_logits_kernel(const int* __restrict__ ei, const int* __restrict__ et,
                        const u16* __restrict__ xl, const u16* __restrict__ xr,
                        const float* __restrict__ erel, const float* __restrict__ att,
                        float* __restrict__ logits, u32* __restrict__ lmax)
{
    __shared__ float att_s[DD];
    int tid = threadIdx.x;
    if (tid < DD) att_s[tid] = att[tid];
    __syncthreads();
    int i = blockIdx.x * 256 + tid;
    if (i >= EE * HH) return;
    int eid = i >> 2, h = i & 3;
    int src = ei[eid], dst = ei[EE + eid], t = et[eid];
    const u16*   pl = xl + (size_t)src * DD + h * CC;
    const u16*   pr = xr + (size_t)dst * DD + h * CC;
    const float* pe = erel + (size_t)t * DD + h * CC;
    const float* pa = att_s + h * CC;
    float v = 0.f;
    #pragma unroll
    for (int j = 0; j < CC; j++) {
        float m = bf2f(pl[j]) + bf2f(pr[j]) + pe[j];
        m = m > 0.f ? m : 0.2f * m;     // leaky_relu BEFORE attention dot
        v += m * pa[j];
    }
    logits[i] = v;
    atomicMax(&lmax[(size_t)dst * HH + h], flipf(v));
}

// ---------------- exp(logit - max) and segment denom (NaN-proof)
__global__ __launch_bounds__(256)
void edge_softmax_kernel(const int* __restrict__ ei, float* __restrict__ logits,
                         const u32* __restrict__ lmax, float* __restrict__ denom)
{
    int i = blockIdx.x * 256 + threadIdx.x;
    if (i >= EE * HH) return;
    int eid = i >> 2, h = i & 3;
    int dst = ei[EE + eid];
    float lm = unflipf(lmax[(size_t)dst * HH + h]);
    // fminf returns the non-NaN operand: even garbage lm cannot yield NaN/inf
    float ex = __expf(fminf(0.f, logits[i] - lm));
    logits[i] = ex;
    atomicAdd(&denom[(size_t)dst * HH + h], ex);
}

// ---------------- weighted scatter-aggregate (2 edges per 256-thread block)
__global__ __launch_bounds__(256)
void edge_aggregate_kernel(const int* __restrict__ ei, const float* __restrict__ logits,
                           const float* __restrict__ denom, const u16* __restrict__ xl,
                           float* __restrict__ out_acc)
{
    int tid = threadIdx.x;
    int eid = blockIdx.x * 2 + (tid >> 7);
    int c = tid & 127;
    if (eid >= EE) return;
    int src = ei[eid], dst = ei[EE + eid];
    int h = c >> 5;
    float alpha = logits[(size_t)eid * HH + h]
                / fmaxf(denom[(size_t)dst * HH + h], 1e-30f);
    atomicAdd(&out_acc[(size_t)dst * DD + c], alpha * bf2f(xl[(size_t)src * DD + c]));
}

// ---------------- bias + activation / output conversion (in-place safe: xnext==out_acc)
__global__ __launch_bounds__(256)
void finalize_kernel(const float* __restrict__ out_acc, const float* __restrict__ bias,
                     float* __restrict__ xnext, float* __restrict__ outp, int is_last)
{
    int i = blockIdx.x * 256 + threadIdx.x;
    if (i >= NN * DD) return;
    float v = out_acc[i] + bias[i & (DD - 1)];
    // finite-clamp: fmaxf/fminf return the non-NaN operand, so any stray NaN
    // becomes a finite (diagnosable) value instead of poisoning the output
    v = fminf(fmaxf(v, -1e4f), 1e4f);
    if (is_last) {
        outp[i] = v;
    } else {
        xnext[i] = v > 0.f ? v : __expf(v) - 1.f;   // elu between layers
    }
}

extern "C" void kernel_launch(void* const* d_in, const int* in_sizes, int n_in,
                              void* d_out, int out_size, void* d_ws, size_t ws_size,
                              hipStream_t stream)
{
    const int*   entity        = (const int*)d_in[0];
    const int*   edge_index    = (const int*)d_in[1];
    const int*   edge_type     = (const int*)d_in[2];
    const float* node_features = (const float*)d_in[3];
    const float* rel_emb       = (const float*)d_in[4];
    const float* proj_w        = (const float*)d_in[5];
    const float* proj_b        = (const float*)d_in[6];
    const float* w_l           = (const float*)d_in[7];
    const float* b_l           = (const float*)d_in[8];
    const float* w_r           = (const float*)d_in[9];
    const float* b_r           = (const float*)d_in[10];
    const float* w_e           = (const float*)d_in[11];
    const float* att           = (const float*)d_in[12];
    const float* bias          = (const float*)d_in[13];

    // workspace (~63 MB):
    //   x (fp32, doubles as out_acc) | logits | erel | lmax | denom | xl (bf16) | xr (bf16)
    float* x      = (float*)d_ws;                          // NN*DD fp32
    float* logits = x + (size_t)NN * DD;                   // EE*HH fp32
    float* erel   = logits + (size_t)EE * HH;              // LL*RR*DD fp32
    u32*   lmax   = (u32*)(erel + (size_t)LL * RR * DD);   // NN*HH u32
    float* denom  = (float*)(lmax + (size_t)NN * HH);      // NN*HH fp32
    u16*   xl     = (u16*)(denom + (size_t)NN * HH);       // NN*DD bf16
    u16*   xr     = xl + (size_t)NN * DD;                  // NN*DD bf16

    relproj_kernel<<<LL * RR, 128, 0, stream>>>(rel_emb, w_e, erel);

    // x = node_features[entity] @ proj_w + proj_b   (fp32 out)
    gemm128_kernel<false><<<(NN + TILE_M - 1) / TILE_M, 256, 0, stream>>>(
        node_features, entity, FF, proj_w, proj_b, x, NN, FF);

    for (int l = 0; l < LL; l++) {
        gemm128_kernel<true><<<(NN + TILE_M - 1) / TILE_M, 256, 0, stream>>>(
            x, nullptr, DD, w_l + (size_t)l * DD * DD, b_l + l * DD, xl, NN, DD);
        gemm128_kernel<true><<<(NN + TILE_M - 1) / TILE_M, 256, 0, stream>>>(
            x, nullptr, DD, w_r + (size_t)l * DD * DD, b_r + l * DD, xr, NN, DD);

        // x is dead now; reuse it as out_acc
        hipMemsetAsync(x, 0, (size_t)NN * DD * sizeof(float), stream);
        // lmax (flipped rep: 0 is the max-identity) and denom, contiguous
        hipMemsetAsync(lmax, 0, (size_t)NN * HH * sizeof(u32) * 2, stream);

        edge_logits_kernel<<<(EE * HH + 255) / 256, 256, 0, stream>>>(
            edge_index, edge_type, xl, xr, erel + (size_t)l * RR * DD,
            att + (size_t)l * DD, logits, lmax);
        edge_softmax_kernel<<<(EE * HH + 255) / 256, 256, 0, stream>>>(
            edge_index, logits, lmax, denom);
        edge_aggregate_kernel<<<EE / 2, 256, 0, stream>>>(
            edge_index, logits, denom, xl, x);
        finalize_kernel<<<(NN * DD + 255) / 256, 256, 0, stream>>>(
            x, bias + (size_t)l * DD, x, (float*)d_out, l == LL - 1);
    }
}

// Round 4
// 883.602 us; speedup vs baseline: 1.3835x; 1.3835x over previous
//
#include <hip/hip_runtime.h>

#define NN 50000
#define FF 300
#define DD 128
#define HH 4
#define CC 32
#define EE 640000
#define RR 200
#define LL 2

typedef unsigned short u16;
typedef unsigned int u32;

__device__ __forceinline__ float bf2f(u16 u) {
    union { u32 i; float f; } v; v.i = ((u32)u) << 16; return v.f;
}
__device__ __forceinline__ u16 f2bf(float f) {
    u32 u = __float_as_uint(f);
    u32 r = (u >> 16) & 1u;
    u += 0x7fffu + r;
    return (u16)(u >> 16);
}

// ---------------- relation projection: erel[l*RR+r][d] = rel_emb[r,:] @ w_e[l][:,d]
__global__ __launch_bounds__(128)
void relproj_kernel(const float* __restrict__ rel_emb,
                    const float* __restrict__ w_e,
                    float* __restrict__ erel)
{
    int lr = blockIdx.x;            // l*RR + r
    int l = lr / RR, r = lr - l * RR;
    int d = threadIdx.x;
    __shared__ float rv[DD];
    rv[d] = rel_emb[r * DD + d];
    __syncthreads();
    const float* W = w_e + (size_t)l * DD * DD;
    float acc = 0.f;
    #pragma unroll 8
    for (int k = 0; k < DD; k++) acc += rv[k] * W[k * DD + d];
    erel[(size_t)lr * DD + d] = acc;
}

// ---------------- tiled GEMM: C[M,128] = A[M,K] @ B[K,128] + bvec  (fp32 in)
#define TILE_M 64
#define TILE_K 16
template<bool OUTBF16>
__global__ __launch_bounds__(256)
void gemm128_kernel(const float* __restrict__ A, const int* __restrict__ rowidx,
                    int lda, const float* __restrict__ B,
                    const float* __restrict__ bvec,
                    void* __restrict__ C_, int M, int K)
{
    __shared__ float As[TILE_K][TILE_M + 4];
    __shared__ float Bs[TILE_K][DD];
    __shared__ int rmap[TILE_M];

    int tid = threadIdx.x;
    int m0 = blockIdx.x * TILE_M;
    if (tid < TILE_M) {
        int r = m0 + tid;
        rmap[tid] = (r < M) ? (rowidx ? rowidx[r] : r) : 0;
    }
    __syncthreads();

    int tx = tid & 31;
    int ty = tid >> 5;
    float acc[8][4];
    #pragma unroll
    for (int i = 0; i < 8; i++)
        #pragma unroll
        for (int j = 0; j < 4; j++) acc[i][j] = 0.f;

    int arow = tid >> 2;
    int akq  = (tid & 3) * 4;
    int brow = tid >> 4;
    int bc   = (tid & 15) * 8;

    for (int kk = 0; kk < K; kk += TILE_K) {
        {
            int rid = rmap[arow];
            #pragma unroll
            for (int j = 0; j < 4; j++) {
                int k = kk + akq + j;
                As[akq + j][arow] = (k < K) ? A[(size_t)rid * lda + k] : 0.f;
            }
        }
        {
            int k = kk + brow;
            #pragma unroll
            for (int j = 0; j < 8; j++)
                Bs[brow][bc + j] = (k < K) ? B[(size_t)k * DD + bc + j] : 0.f;
        }
        __syncthreads();
        #pragma unroll
        for (int k = 0; k < TILE_K; k++) {
            float4 a0 = *(const float4*)&As[k][ty * 8];
            float4 a1 = *(const float4*)&As[k][ty * 8 + 4];
            float4 bq = *(const float4*)&Bs[k][tx * 4];
            float a[8] = {a0.x, a0.y, a0.z, a0.w, a1.x, a1.y, a1.z, a1.w};
            float b[4] = {bq.x, bq.y, bq.z, bq.w};
            #pragma unroll
            for (int i = 0; i < 8; i++)
                #pragma unroll
                for (int j = 0; j < 4; j++) acc[i][j] += a[i] * b[j];
        }
        __syncthreads();
    }

    float bv[4];
    #pragma unroll
    for (int j = 0; j < 4; j++) bv[j] = bvec ? bvec[tx * 4 + j] : 0.f;
    #pragma unroll
    for (int i = 0; i < 8; i++) {
        int r = m0 + ty * 8 + i;
        if (r < M) {
            float o0 = acc[i][0] + bv[0], o1 = acc[i][1] + bv[1];
            float o2 = acc[i][2] + bv[2], o3 = acc[i][3] + bv[3];
            if (OUTBF16) {
                union { u16 h[4]; unsigned long long v; } p;
                p.h[0] = f2bf(o0); p.h[1] = f2bf(o1); p.h[2] = f2bf(o2); p.h[3] = f2bf(o3);
                *(unsigned long long*)((u16*)C_ + (size_t)r * DD + tx * 4) = p.v;
            } else {
                *(float4*)((float*)C_ + (size_t)r * DD + tx * 4) =
                    make_float4(o0, o1, o2, o3);
            }
        }
    }
}

// ---------------- CSR build: histogram -> scan -> scatter (once per call)
__global__ __launch_bounds__(256)
void hist_kernel(const int* __restrict__ ei, int* __restrict__ counts)
{
    int e = blockIdx.x * 256 + threadIdx.x;
    if (e < EE) atomicAdd(&counts[ei[EE + e]], 1);
}

#define SCAN_T 1024
__global__ __launch_bounds__(SCAN_T)
void scan_kernel(const int* __restrict__ counts, int* __restrict__ offsets)
{
    __shared__ int part[SCAN_T];
    int t = threadIdx.x;
    const int chunk = (NN + SCAN_T - 1) / SCAN_T;
    int b = t * chunk, e = min(b + chunk, NN);
    int mysum = 0;
    for (int i = b; i < e; i++) mysum += counts[i];
    part[t] = mysum;
    __syncthreads();
    for (int off = 1; off < SCAN_T; off <<= 1) {
        int v = (t >= off) ? part[t - off] : 0;
        __syncthreads();
        part[t] += v;
        __syncthreads();
    }
    int running = part[t] - mysum;      // exclusive prefix of this chunk
    for (int i = b; i < e; i++) { offsets[i] = running; running += counts[i]; }
    if (t == SCAN_T - 1) offsets[NN] = EE;
}

__global__ __launch_bounds__(256)
void scatter_kernel(const int* __restrict__ ei, const int* __restrict__ offsets,
                    int* __restrict__ fill, int* __restrict__ perm)
{
    int e = blockIdx.x * 256 + threadIdx.x;
    if (e >= EE) return;
    int d = ei[EE + e];
    int pos = offsets[d] + atomicAdd(&fill[d], 1);
    perm[pos] = e;
}

// ---------------- per-(edge,head) raw logits (no atomics)
__global__ __launch_bounds__(256)
void edge_logits_kernel(const int* __restrict__ ei, const int* __restrict__ et,
                        const u16* __restrict__ xl, const u16* __restrict__ xr,
                        const float* __restrict__ erel, const float* __restrict__ att,
                        float* __restrict__ logits)
{
    __shared__ float att_s[DD];
    int tid = threadIdx.x;
    if (tid < DD) att_s[tid] = att[tid];
    __syncthreads();
    int i = blockIdx.x * 256 + tid;
    if (i >= EE * HH) return;
    int eid = i >> 2, h = i & 3;
    int src = ei[eid], dst = ei[EE + eid], t = et[eid];
    const u16*   pl = xl + (size_t)src * DD + h * CC;
    const u16*   pr = xr + (size_t)dst * DD + h * CC;
    const float* pe = erel + (size_t)t * DD + h * CC;
    const float* pa = att_s + h * CC;
    float v = 0.f;
    #pragma unroll
    for (int j = 0; j < CC; j++) {
        float m = bf2f(pl[j]) + bf2f(pr[j]) + pe[j];
        m = m > 0.f ? m : 0.2f * m;     // leaky_relu BEFORE attention dot
        v += m * pa[j];
    }
    logits[i] = v;
}

// ---------------- fused per-node softmax + aggregate + bias + activation
// one wave (64 lanes) per destination node; 4 nodes per 256-thread block
__global__ __launch_bounds__(256)
void node_kernel(const int* __restrict__ ei, const int* __restrict__ perm,
                 const int* __restrict__ offsets, const float* __restrict__ logits,
                 const u16* __restrict__ xl, const float* __restrict__ bias,
                 float* __restrict__ xnext, float* __restrict__ outp, int is_last)
{
    int tid = threadIdx.x;
    int node = blockIdx.x * 4 + (tid >> 6);
    int lane = tid & 63;
    if (node >= NN) return;
    int beg = offsets[node], end = offsets[node + 1];

    // phase A: per-head max over incoming edges (lane-parallel)
    float mx0 = -1e30f, mx1 = -1e30f, mx2 = -1e30f, mx3 = -1e30f;
    for (int i = beg + lane; i < end; i += 64) {
        float4 lg = *(const float4*)&logits[(size_t)perm[i] * 4];
        mx0 = fmaxf(mx0, lg.x); mx1 = fmaxf(mx1, lg.y);
        mx2 = fmaxf(mx2, lg.z); mx3 = fmaxf(mx3, lg.w);
    }
    #pragma unroll
    for (int off = 1; off < 64; off <<= 1) {
        mx0 = fmaxf(mx0, __shfl_xor(mx0, off, 64));
        mx1 = fmaxf(mx1, __shfl_xor(mx1, off, 64));
        mx2 = fmaxf(mx2, __shfl_xor(mx2, off, 64));
        mx3 = fmaxf(mx3, __shfl_xor(mx3, off, 64));
    }

    // phase B: exp-sum (lane-parallel)
    float sm0 = 0.f, sm1 = 0.f, sm2 = 0.f, sm3 = 0.f;
    for (int i = beg + lane; i < end; i += 64) {
        float4 lg = *(const float4*)&logits[(size_t)perm[i] * 4];
        sm0 += __expf(lg.x - mx0); sm1 += __expf(lg.y - mx1);
        sm2 += __expf(lg.z - mx2); sm3 += __expf(lg.w - mx3);
    }
    #pragma unroll
    for (int off = 1; off < 64; off <<= 1) {
        sm0 += __shfl_xor(sm0, off, 64);
        sm1 += __shfl_xor(sm1, off, 64);
        sm2 += __shfl_xor(sm2, off, 64);
        sm3 += __shfl_xor(sm3, off, 64);
    }

    // this lane handles channels 2*lane, 2*lane+1 -> head = lane>>4
    int h = lane >> 4;
    float mh = (h == 0) ? mx0 : (h == 1) ? mx1 : (h == 2) ? mx2 : mx3;
    float sh = (h == 0) ? sm0 : (h == 1) ? sm1 : (h == 2) ? sm2 : sm3;
    float rh = 1.f / fmaxf(sh, 1e-30f);

    // phase C: channel-parallel weighted aggregate (sequential over edges)
    float a0 = 0.f, a1 = 0.f;
    for (int i = beg; i < end; i++) {
        int eid = perm[i];
        int src = ei[eid];
        float alpha = __expf(logits[(size_t)eid * 4 + h] - mh) * rh;
        u32 p = *(const u32*)&xl[(size_t)src * DD + lane * 2];
        a0 += alpha * bf2f((u16)p);
        a1 += alpha * bf2f((u16)(p >> 16));
    }

    int ch = lane * 2;
    float v0 = a0 + bias[ch], v1 = a1 + bias[ch + 1];
    if (is_last) {
        outp[(size_t)node * DD + ch]     = v0;
        outp[(size_t)node * DD + ch + 1] = v1;
    } else {
        xnext[(size_t)node * DD + ch]     = v0 > 0.f ? v0 : __expf(v0) - 1.f;
        xnext[(size_t)node * DD + ch + 1] = v1 > 0.f ? v1 : __expf(v1) - 1.f;
    }
}

extern "C" void kernel_launch(void* const* d_in, const int* in_sizes, int n_in,
                              void* d_out, int out_size, void* d_ws, size_t ws_size,
                              hipStream_t stream)
{
    const int*   entity        = (const int*)d_in[0];
    const int*   edge_index    = (const int*)d_in[1];
    const int*   edge_type     = (const int*)d_in[2];
    const float* node_features = (const float*)d_in[3];
    const float* rel_emb       = (const float*)d_in[4];
    const float* proj_w        = (const float*)d_in[5];
    const float* proj_b        = (const float*)d_in[6];
    const float* w_l           = (const float*)d_in[7];
    const float* b_l           = (const float*)d_in[8];
    const float* w_r           = (const float*)d_in[9];
    const float* b_r           = (const float*)d_in[10];
    const float* w_e           = (const float*)d_in[11];
    const float* att           = (const float*)d_in[12];
    const float* bias          = (const float*)d_in[13];

    // workspace (~65 MB), 16B-aligned segments first:
    float* x      = (float*)d_ws;                          // NN*DD fp32 (ping-pong via in-place)
    float* logits = x + (size_t)NN * DD;                   // EE*HH fp32
    float* erel   = logits + (size_t)EE * HH;              // LL*RR*DD fp32
    u16*   xl     = (u16*)(erel + (size_t)LL * RR * DD);   // NN*DD bf16
    u16*   xr     = xl + (size_t)NN * DD;                  // NN*DD bf16
    int*   perm   = (int*)(xr + (size_t)NN * DD);          // EE int
    int*   counts = perm + (size_t)EE;                     // NN int
    int*   fill   = counts + NN;                           // NN int
    int*   offsets= fill + NN;                             // NN+1 int

    // ---- CSR build (edges constant across layers: once per call)
    hipMemsetAsync(counts, 0, (size_t)NN * 2 * sizeof(int), stream);  // counts + fill
    hist_kernel<<<(EE + 255) / 256, 256, 0, stream>>>(edge_index, counts);
    scan_kernel<<<1, SCAN_T, 0, stream>>>(counts, offsets);
    scatter_kernel<<<(EE + 255) / 256, 256, 0, stream>>>(edge_index, offsets, fill, perm);

    relproj_kernel<<<LL * RR, 128, 0, stream>>>(rel_emb, w_e, erel);

    // x = node_features[entity] @ proj_w + proj_b   (fp32 out)
    gemm128_kernel<false><<<(NN + TILE_M - 1) / TILE_M, 256, 0, stream>>>(
        node_features, entity, FF, proj_w, proj_b, x, NN, FF);

    for (int l = 0; l < LL; l++) {
        gemm128_kernel<true><<<(NN + TILE_M - 1) / TILE_M, 256, 0, stream>>>(
            x, nullptr, DD, w_l + (size_t)l * DD * DD, b_l + l * DD, xl, NN, DD);
        gemm128_kernel<true><<<(NN + TILE_M - 1) / TILE_M, 256, 0, stream>>>(
            x, nullptr, DD, w_r + (size_t)l * DD * DD, b_r + l * DD, xr, NN, DD);

        edge_logits_kernel<<<(EE * HH + 255) / 256, 256, 0, stream>>>(
            edge_index, edge_type, xl, xr, erel + (size_t)l * RR * DD,
            att + (size_t)l * DD, logits);

        // x is dead after the two GEMMs; node_kernel rewrites it (or d_out)
        node_kernel<<<(NN + 3) / 4, 256, 0, stream>>>(
            edge_index, perm, offsets, logits, xl, bias + (size_t)l * DD,
            x, (float*)d_out, l == LL - 1);
    }
}

// Round 5
// 636.875 us; speedup vs baseline: 1.9194x; 1.3874x over previous
//
#include <hip/hip_runtime.h>

#define NN 50000
#define FF 300
#define DD 128
#define HH 4
#define CC 32
#define EE 640000
#define RR 200
#define LL 2

typedef unsigned short u16;
typedef unsigned int u32;
typedef unsigned long long u64;
typedef __attribute__((ext_vector_type(8))) short short8;   // 8 bf16 (4 VGPRs)
typedef __attribute__((ext_vector_type(4))) float floatx4;  // MFMA accumulator

__device__ __forceinline__ float bf2f(u16 u) {
    union { u32 i; float f; } v; v.i = ((u32)u) << 16; return v.f;
}
__device__ __forceinline__ u16 f2bf(float f) {
    u32 u = __float_as_uint(f);
    u32 r = (u >> 16) & 1u;
    u += 0x7fffu + r;
    return (u16)(u >> 16);
}

// ---------------- relation projection: erel[l*RR+r][d] = rel_emb[r,:] @ w_e[l][:,d]
__global__ __launch_bounds__(128)
void relproj_kernel(const float* __restrict__ rel_emb,
                    const float* __restrict__ w_e,
                    float* __restrict__ erel)
{
    int lr = blockIdx.x;            // l*RR + r
    int l = lr / RR, r = lr - l * RR;
    int d = threadIdx.x;
    __shared__ float rv[DD];
    rv[d] = rel_emb[r * DD + d];
    __syncthreads();
    const float* W = w_e + (size_t)l * DD * DD;
    float acc = 0.f;
    #pragma unroll 8
    for (int k = 0; k < DD; k++) acc += rv[k] * W[k * DD + d];
    erel[(size_t)lr * DD + d] = acc;
}

// ---------------- MFMA bf16 GEMM: C[M,128] = A[M,K] @ B[K,128] + bias, out bf16
// Block: 128 rows x 128 cols, 4 waves, each wave 64x64 via 4x4 grid of 16x16x32.
// A: fp32 (optional row gather) or bf16. B: fp32 [K][128], converted in staging.
// LDS pads leading dim to 40 (80 B): fragment reads are 2-way conflict (free, m136).
template<bool ABF16, bool GATHER>
__global__ __launch_bounds__(256)
void gemm_mfma_kernel(const void* __restrict__ A_, const int* __restrict__ rowidx,
                      int lda, int K, const float* __restrict__ B,
                      const float* __restrict__ bias, u16* __restrict__ Cout, int M)
{
    __shared__ u16 As[128][40];
    __shared__ u16 Bs[128][40];   // Bs[n][k]
    int tid  = threadIdx.x;
    int m0   = blockIdx.x * 128;
    int wave = tid >> 6, lane = tid & 63;
    int quad = lane >> 4, l16 = lane & 15;
    int wrow = (wave >> 1) * 64, wcol = (wave & 1) * 64;

    floatx4 acc[4][4];
    #pragma unroll
    for (int i = 0; i < 4; i++)
        #pragma unroll
        for (int j = 0; j < 4; j++) acc[i][j] = (floatx4){0.f, 0.f, 0.f, 0.f};

    // A-staging assignment: thread -> (row ar, k-half ahalf)
    int ar = tid >> 1, ahalf = tid & 1;
    int arow = m0 + ar;
    int rid = (arow < M) ? (GATHER ? rowidx[arow] : arow) : 0;
    // B-staging assignment: thread -> (k row bk, 16 cols from bn0)
    int bk = tid >> 3, bn0 = (tid & 7) * 16;

    for (int kk = 0; kk < K; kk += 32) {
        // ---- stage A (128 x 32)
        {
            int kb = kk + ahalf * 16;
            u16 tmp[16];
            if (ABF16) {
                const u16* Ap = (const u16*)A_ + (size_t)rid * lda + kb;
                if (kb + 16 <= K) {
                    *(short8*)&tmp[0] = *(const short8*)Ap;
                    *(short8*)&tmp[8] = *(const short8*)(Ap + 8);
                } else {
                    #pragma unroll
                    for (int j = 0; j < 16; j++) tmp[j] = (kb + j < K) ? Ap[j] : (u16)0;
                }
            } else {
                const float* Ap = (const float*)A_ + (size_t)rid * lda + kb;
                if (kb + 16 <= K) {
                    #pragma unroll
                    for (int q = 0; q < 4; q++) {
                        float4 f = *(const float4*)(Ap + q * 4);
                        tmp[q*4+0] = f2bf(f.x); tmp[q*4+1] = f2bf(f.y);
                        tmp[q*4+2] = f2bf(f.z); tmp[q*4+3] = f2bf(f.w);
                    }
                } else {
                    #pragma unroll
                    for (int j = 0; j < 16; j++) tmp[j] = (kb + j < K) ? f2bf(Ap[j]) : (u16)0;
                }
            }
            *(short8*)&As[ar][ahalf * 16]     = *(short8*)&tmp[0];
            *(short8*)&As[ar][ahalf * 16 + 8] = *(short8*)&tmp[8];
        }
        // ---- stage B transposed (Bs[n][k], 128 x 32)
        {
            int k = kk + bk;
            float vals[16];
            if (k < K) {
                const float* Bp = B + (size_t)k * DD + bn0;
                #pragma unroll
                for (int q = 0; q < 4; q++) {
                    float4 f = *(const float4*)(Bp + q * 4);
                    vals[q*4+0] = f.x; vals[q*4+1] = f.y;
                    vals[q*4+2] = f.z; vals[q*4+3] = f.w;
                }
            } else {
                #pragma unroll
                for (int j = 0; j < 16; j++) vals[j] = 0.f;
            }
            #pragma unroll
            for (int j = 0; j < 16; j++) Bs[bn0 + j][bk] = f2bf(vals[j]);
        }
        __syncthreads();
        // ---- MFMA inner: A[m=l16][k=quad*8+j], B[n=l16][k=quad*8+j]
        short8 af[4], bfr[4];
        #pragma unroll
        for (int i = 0; i < 4; i++)
            af[i] = *(const short8*)&As[wrow + i * 16 + l16][quad * 8];
        #pragma unroll
        for (int j = 0; j < 4; j++)
            bfr[j] = *(const short8*)&Bs[wcol + j * 16 + l16][quad * 8];
        #pragma unroll
        for (int i = 0; i < 4; i++)
            #pragma unroll
            for (int j = 0; j < 4; j++)
                acc[i][j] = __builtin_amdgcn_mfma_f32_16x16x32_bf16(
                    af[i], bfr[j], acc[i][j], 0, 0, 0);
        __syncthreads();
    }

    // ---- epilogue: C/D layout col=lane&15, row=quad*4+reg (m89)
    #pragma unroll
    for (int i = 0; i < 4; i++) {
        #pragma unroll
        for (int rr = 0; rr < 4; rr++) {
            int row = m0 + wrow + i * 16 + quad * 4 + rr;
            if (row < M) {
                #pragma unroll
                for (int j = 0; j < 4; j++) {
                    int col = wcol + j * 16 + l16;
                    Cout[(size_t)row * DD + col] = f2bf(acc[i][j][rr] + bias[col]);
                }
            }
        }
    }
}

// ---------------- CSR build: histogram -> scan -> scatter (once per call)
__global__ __launch_bounds__(256)
void hist_kernel(const int* __restrict__ ei, int* __restrict__ counts)
{
    int e = blockIdx.x * 256 + threadIdx.x;
    if (e < EE) atomicAdd(&counts[ei[EE + e]], 1);
}

#define SCAN_T 1024
__global__ __launch_bounds__(SCAN_T)
void scan_kernel(const int* __restrict__ counts, int* __restrict__ offsets)
{
    __shared__ int part[SCAN_T];
    int t = threadIdx.x;
    const int chunk = (NN + SCAN_T - 1) / SCAN_T;
    int b = t * chunk, e = min(b + chunk, NN);
    int mysum = 0;
    for (int i = b; i < e; i++) mysum += counts[i];
    part[t] = mysum;
    __syncthreads();
    for (int off = 1; off < SCAN_T; off <<= 1) {
        int v = (t >= off) ? part[t - off] : 0;
        __syncthreads();
        part[t] += v;
        __syncthreads();
    }
    int running = part[t] - mysum;
    for (int i = b; i < e; i++) { offsets[i] = running; running += counts[i]; }
    if (t == SCAN_T - 1) offsets[NN] = EE;
}

__global__ __launch_bounds__(256)
void scatter_kernel(const int* __restrict__ ei, const int* __restrict__ offsets,
                    int* __restrict__ fill, int* __restrict__ perm)
{
    int e = blockIdx.x * 256 + threadIdx.x;
    if (e >= EE) return;
    int d = ei[EE + e];
    int pos = offsets[d] + atomicAdd(&fill[d], 1);
    perm[pos] = e;
}

// ---------------- per-(edge,head) raw logits, vectorized loads
__global__ __launch_bounds__(256)
void edge_logits_kernel(const int* __restrict__ ei, const int* __restrict__ et,
                        const u16* __restrict__ xl, const u16* __restrict__ xr,
                        const float* __restrict__ erel, const float* __restrict__ att,
                        float* __restrict__ logits)
{
    __shared__ float att_s[DD];
    int tid = threadIdx.x;
    if (tid < DD) att_s[tid] = att[tid];
    __syncthreads();
    int i = blockIdx.x * 256 + tid;
    if (i >= EE * HH) return;
    int eid = i >> 2, h = i & 3;
    int src = ei[eid], dst = ei[EE + eid], t = et[eid];
    const u16*   pl = xl + (size_t)src * DD + h * CC;
    const u16*   pr = xr + (size_t)dst * DD + h * CC;
    const float* pe = erel + (size_t)t * DD + h * CC;
    const float* pa = att_s + h * CC;
    float v = 0.f;
    #pragma unroll
    for (int j = 0; j < CC; j += 4) {
        u64 plv = *(const u64*)(pl + j);
        u64 prv = *(const u64*)(pr + j);
        float4 pev = *(const float4*)(pe + j);
        float4 pav = *(const float4*)(pa + j);
        float m0 = bf2f((u16)plv)         + bf2f((u16)prv)         + pev.x;
        float m1 = bf2f((u16)(plv >> 16)) + bf2f((u16)(prv >> 16)) + pev.y;
        float m2 = bf2f((u16)(plv >> 32)) + bf2f((u16)(prv >> 32)) + pev.z;
        float m3 = bf2f((u16)(plv >> 48)) + bf2f((u16)(prv >> 48)) + pev.w;
        m0 = m0 > 0.f ? m0 : 0.2f * m0;   // leaky_relu BEFORE attention dot
        m1 = m1 > 0.f ? m1 : 0.2f * m1;
        m2 = m2 > 0.f ? m2 : 0.2f * m2;
        m3 = m3 > 0.f ? m3 : 0.2f * m3;
        v += m0 * pav.x + m1 * pav.y + m2 * pav.z + m3 * pav.w;
    }
    logits[i] = v;
}

// ---------------- fused per-node softmax + aggregate + bias + activation
// one wave per destination node; fast path keeps edges register-resident
__global__ __launch_bounds__(256)
void node_kernel(const int* __restrict__ ei, const int* __restrict__ perm,
                 const int* __restrict__ offsets, const float* __restrict__ logits,
                 const u16* __restrict__ xl, const float* __restrict__ bias,
                 u16* __restrict__ xnext, float* __restrict__ outp, int is_last)
{
    int tid = threadIdx.x;
    int node = blockIdx.x * 4 + (tid >> 6);
    int lane = tid & 63;
    if (node >= NN) return;
    int beg = offsets[node], end = offsets[node + 1];
    int cnt = end - beg;
    int h = lane >> 4;
    float a0 = 0.f, a1 = 0.f;

    if (cnt <= 64) {
        // one edge per lane, everything register-resident
        int eid = (lane < cnt) ? perm[beg + lane] : -1;
        int src = (eid >= 0) ? ei[eid] : 0;
        float4 lg = (eid >= 0) ? *(const float4*)&logits[(size_t)eid * 4]
                               : make_float4(-1e30f, -1e30f, -1e30f, -1e30f);
        float mx0 = lg.x, mx1 = lg.y, mx2 = lg.z, mx3 = lg.w;
        #pragma unroll
        for (int off = 1; off < 64; off <<= 1) {
            mx0 = fmaxf(mx0, __shfl_xor(mx0, off, 64));
            mx1 = fmaxf(mx1, __shfl_xor(mx1, off, 64));
            mx2 = fmaxf(mx2, __shfl_xor(mx2, off, 64));
            mx3 = fmaxf(mx3, __shfl_xor(mx3, off, 64));
        }
        float e0 = (eid >= 0) ? __expf(lg.x - mx0) : 0.f;
        float e1 = (eid >= 0) ? __expf(lg.y - mx1) : 0.f;
        float e2 = (eid >= 0) ? __expf(lg.z - mx2) : 0.f;
        float e3 = (eid >= 0) ? __expf(lg.w - mx3) : 0.f;
        float s0 = e0, s1 = e1, s2 = e2, s3 = e3;
        #pragma unroll
        for (int off = 1; off < 64; off <<= 1) {
            s0 += __shfl_xor(s0, off, 64);
            s1 += __shfl_xor(s1, off, 64);
            s2 += __shfl_xor(s2, off, 64);
            s3 += __shfl_xor(s3, off, 64);
        }
        float sh = (h == 0) ? s0 : (h == 1) ? s1 : (h == 2) ? s2 : s3;
        float rh = 1.f / fmaxf(sh, 1e-30f);
        for (int i = 0; i < cnt; i++) {
            int s = __shfl(src, i, 64);
            float n0 = __shfl(e0, i, 64), n1 = __shfl(e1, i, 64);
            float n2 = __shfl(e2, i, 64), n3 = __shfl(e3, i, 64);
            float en = (h == 0) ? n0 : (h == 1) ? n1 : (h == 2) ? n2 : n3;
            float alpha = en * rh;
            u32 p = *(const u32*)&xl[(size_t)s * DD + lane * 2];
            a0 += alpha * bf2f((u16)p);
            a1 += alpha * bf2f((u16)(p >> 16));
        }
    } else {
        // slow path (deg > 64): 3-phase over global logits
        float mx0 = -1e30f, mx1 = -1e30f, mx2 = -1e30f, mx3 = -1e30f;
        for (int i = beg + lane; i < end; i += 64) {
            float4 lg = *(const float4*)&logits[(size_t)perm[i] * 4];
            mx0 = fmaxf(mx0, lg.x); mx1 = fmaxf(mx1, lg.y);
            mx2 = fmaxf(mx2, lg.z); mx3 = fmaxf(mx3, lg.w);
        }
        #pragma unroll
        for (int off = 1; off < 64; off <<= 1) {
            mx0 = fmaxf(mx0, __shfl_xor(mx0, off, 64));
            mx1 = fmaxf(mx1, __shfl_xor(mx1, off, 64));
            mx2 = fmaxf(mx2, __shfl_xor(mx2, off, 64));
            mx3 = fmaxf(mx3, __shfl_xor(mx3, off, 64));
        }
        float s0 = 0.f, s1 = 0.f, s2 = 0.f, s3 = 0.f;
        for (int i = beg + lane; i < end; i += 64) {
            float4 lg = *(const float4*)&logits[(size_t)perm[i] * 4];
            s0 += __expf(lg.x - mx0); s1 += __expf(lg.y - mx1);
            s2 += __expf(lg.z - mx2); s3 += __expf(lg.w - mx3);
        }
        #pragma unroll
        for (int off = 1; off < 64; off <<= 1) {
            s0 += __shfl_xor(s0, off, 64);
            s1 += __shfl_xor(s1, off, 64);
            s2 += __shfl_xor(s2, off, 64);
            s3 += __shfl_xor(s3, off, 64);
        }
        float mh = (h == 0) ? mx0 : (h == 1) ? mx1 : (h == 2) ? mx2 : mx3;
        float sh = (h == 0) ? s0 : (h == 1) ? s1 : (h == 2) ? s2 : s3;
        float rh = 1.f / fmaxf(sh, 1e-30f);
        for (int i = beg; i < end; i++) {
            int eid = perm[i];
            int s = ei[eid];
            float alpha = __expf(logits[(size_t)eid * 4 + h] - mh) * rh;
            u32 p = *(const u32*)&xl[(size_t)s * DD + lane * 2];
            a0 += alpha * bf2f((u16)p);
            a1 += alpha * bf2f((u16)(p >> 16));
        }
    }

    int ch = lane * 2;
    float v0 = a0 + bias[ch], v1 = a1 + bias[ch + 1];
    if (is_last) {
        outp[(size_t)node * DD + ch]     = v0;
        outp[(size_t)node * DD + ch + 1] = v1;
    } else {
        float w0 = v0 > 0.f ? v0 : __expf(v0) - 1.f;   // elu between layers
        float w1 = v1 > 0.f ? v1 : __expf(v1) - 1.f;
        u32 pk = (u32)f2bf(w0) | ((u32)f2bf(w1) << 16);
        *(u32*)&xnext[(size_t)node * DD + ch] = pk;
    }
}

extern "C" void kernel_launch(void* const* d_in, const int* in_sizes, int n_in,
                              void* d_out, int out_size, void* d_ws, size_t ws_size,
                              hipStream_t stream)
{
    const int*   entity        = (const int*)d_in[0];
    const int*   edge_index    = (const int*)d_in[1];
    const int*   edge_type     = (const int*)d_in[2];
    const float* node_features = (const float*)d_in[3];
    const float* rel_emb       = (const float*)d_in[4];
    const float* proj_w        = (const float*)d_in[5];
    const float* proj_b        = (const float*)d_in[6];
    const float* w_l           = (const float*)d_in[7];
    const float* b_l           = (const float*)d_in[8];
    const float* w_r           = (const float*)d_in[9];
    const float* b_r           = (const float*)d_in[10];
    const float* w_e           = (const float*)d_in[11];
    const float* att           = (const float*)d_in[12];
    const float* bias          = (const float*)d_in[13];

    // workspace (~52 MB):
    float* logits = (float*)d_ws;                          // EE*HH fp32 (16B-aligned)
    float* erel   = logits + (size_t)EE * HH;              // LL*RR*DD fp32
    u16*   xb     = (u16*)(erel + (size_t)LL * RR * DD);   // NN*DD bf16 (layer input x)
    u16*   xl     = xb + (size_t)NN * DD;                  // NN*DD bf16
    u16*   xr     = xl + (size_t)NN * DD;                  // NN*DD bf16
    int*   perm   = (int*)(xr + (size_t)NN * DD);          // EE int
    int*   counts = perm + (size_t)EE;                     // NN int
    int*   fill   = counts + NN;                           // NN int
    int*   offsets= fill + NN;                             // NN+1 int

    // ---- CSR build (edges constant across layers: once per call)
    hipMemsetAsync(counts, 0, (size_t)NN * 2 * sizeof(int), stream);  // counts + fill
    hist_kernel<<<(EE + 255) / 256, 256, 0, stream>>>(edge_index, counts);
    scan_kernel<<<1, SCAN_T, 0, stream>>>(counts, offsets);
    scatter_kernel<<<(EE + 255) / 256, 256, 0, stream>>>(edge_index, offsets, fill, perm);

    relproj_kernel<<<LL * RR, 128, 0, stream>>>(rel_emb, w_e, erel);

    const int GB = (NN + 127) / 128;
    // xb = bf16(node_features[entity] @ proj_w + proj_b)
    gemm_mfma_kernel<false, true><<<GB, 256, 0, stream>>>(
        node_features, entity, FF, FF, proj_w, proj_b, xb, NN);

    for (int l = 0; l < LL; l++) {
        gemm_mfma_kernel<true, false><<<GB, 256, 0, stream>>>(
            xb, nullptr, DD, DD, w_l + (size_t)l * DD * DD, b_l + l * DD, xl, NN);
        gemm_mfma_kernel<true, false><<<GB, 256, 0, stream>>>(
            xb, nullptr, DD, DD, w_r + (size_t)l * DD * DD, b_r + l * DD, xr, NN);

        edge_logits_kernel<<<(EE * HH + 255) / 256, 256, 0, stream>>>(
            edge_index, edge_type, xl, xr, erel + (size_t)l * RR * DD,
            att + (size_t)l * DD, logits);

        node_kernel<<<(NN + 3) / 4, 256, 0, stream>>>(
            edge_index, perm, offsets, logits, xl, bias + (size_t)l * DD,
            xb, (float*)d_out, l == LL - 1);
    }
}

// Round 6
// 501.162 us; speedup vs baseline: 2.4392x; 1.2708x over previous
//
#include <hip/hip_runtime.h>

#define NN 50000
#define FF 300
#define DD 128
#define HH 4
#define CC 32
#define EE 640000
#define RR 200
#define LL 2

typedef unsigned short u16;
typedef unsigned int u32;
typedef unsigned long long u64;
typedef __attribute__((ext_vector_type(8))) short short8;   // 8 bf16 (4 VGPRs)
typedef __attribute__((ext_vector_type(4))) float floatx4;  // MFMA accumulator

__device__ __forceinline__ float bf2f(u16 u) {
    union { u32 i; float f; } v; v.i = ((u32)u) << 16; return v.f;
}
__device__ __forceinline__ u16 f2bf(float f) {
    u32 u = __float_as_uint(f);
    u32 r = (u >> 16) & 1u;
    u += 0x7fffu + r;
    return (u16)(u >> 16);
}

// ---------------- relation projection (bf16 out): erel[l*RR+r][d] = rel_emb[r,:] @ w_e[l][:,d]
__global__ __launch_bounds__(128)
void relproj_kernel(const float* __restrict__ rel_emb,
                    const float* __restrict__ w_e,
                    u16* __restrict__ erel)
{
    int lr = blockIdx.x;            // l*RR + r
    int l = lr / RR, r = lr - l * RR;
    int d = threadIdx.x;
    __shared__ float rv[DD];
    rv[d] = rel_emb[r * DD + d];
    __syncthreads();
    const float* W = w_e + (size_t)l * DD * DD;
    float acc = 0.f;
    #pragma unroll 8
    for (int k = 0; k < DD; k++) acc += rv[k] * W[k * DD + d];
    erel[(size_t)lr * DD + d] = f2bf(acc);
}

// ---------------- MFMA bf16 GEMM: C[M,128] = A[M,K] @ B[K,128] + bias, out bf16
// Block: 128x128, 4 waves, each wave 64x64 via 4x4 grid of 16x16x32.
template<bool ABF16, bool GATHER>
__global__ __launch_bounds__(256)
void gemm_mfma_kernel(const void* __restrict__ A_, const int* __restrict__ rowidx,
                      int lda, int K, const float* __restrict__ B,
                      const float* __restrict__ bias, u16* __restrict__ Cout, int M)
{
    __shared__ u16 As[128][40];
    __shared__ u16 Bs[128][40];   // Bs[n][k]
    int tid  = threadIdx.x;
    int m0   = blockIdx.x * 128;
    int wave = tid >> 6, lane = tid & 63;
    int quad = lane >> 4, l16 = lane & 15;
    int wrow = (wave >> 1) * 64, wcol = (wave & 1) * 64;

    floatx4 acc[4][4];
    #pragma unroll
    for (int i = 0; i < 4; i++)
        #pragma unroll
        for (int j = 0; j < 4; j++) acc[i][j] = (floatx4){0.f, 0.f, 0.f, 0.f};

    int ar = tid >> 1, ahalf = tid & 1;
    int arow = m0 + ar;
    int rid = (arow < M) ? (GATHER ? rowidx[arow] : arow) : 0;
    int bk = tid >> 3, bn0 = (tid & 7) * 16;

    for (int kk = 0; kk < K; kk += 32) {
        {
            int kb = kk + ahalf * 16;
            u16 tmp[16];
            if (ABF16) {
                const u16* Ap = (const u16*)A_ + (size_t)rid * lda + kb;
                if (kb + 16 <= K) {
                    *(short8*)&tmp[0] = *(const short8*)Ap;
                    *(short8*)&tmp[8] = *(const short8*)(Ap + 8);
                } else {
                    #pragma unroll
                    for (int j = 0; j < 16; j++) tmp[j] = (kb + j < K) ? Ap[j] : (u16)0;
                }
            } else {
                const float* Ap = (const float*)A_ + (size_t)rid * lda + kb;
                if (kb + 16 <= K) {
                    #pragma unroll
                    for (int q = 0; q < 4; q++) {
                        float4 f = *(const float4*)(Ap + q * 4);
                        tmp[q*4+0] = f2bf(f.x); tmp[q*4+1] = f2bf(f.y);
                        tmp[q*4+2] = f2bf(f.z); tmp[q*4+3] = f2bf(f.w);
                    }
                } else {
                    #pragma unroll
                    for (int j = 0; j < 16; j++) tmp[j] = (kb + j < K) ? f2bf(Ap[j]) : (u16)0;
                }
            }
            *(short8*)&As[ar][ahalf * 16]     = *(short8*)&tmp[0];
            *(short8*)&As[ar][ahalf * 16 + 8] = *(short8*)&tmp[8];
        }
        {
            int k = kk + bk;
            float vals[16];
            if (k < K) {
                const float* Bp = B + (size_t)k * DD + bn0;
                #pragma unroll
                for (int q = 0; q < 4; q++) {
                    float4 f = *(const float4*)(Bp + q * 4);
                    vals[q*4+0] = f.x; vals[q*4+1] = f.y;
                    vals[q*4+2] = f.z; vals[q*4+3] = f.w;
                }
            } else {
                #pragma unroll
                for (int j = 0; j < 16; j++) vals[j] = 0.f;
            }
            #pragma unroll
            for (int j = 0; j < 16; j++) Bs[bn0 + j][bk] = f2bf(vals[j]);
        }
        __syncthreads();
        short8 af[4], bfr[4];
        #pragma unroll
        for (int i = 0; i < 4; i++)
            af[i] = *(const short8*)&As[wrow + i * 16 + l16][quad * 8];
        #pragma unroll
        for (int j = 0; j < 4; j++)
            bfr[j] = *(const short8*)&Bs[wcol + j * 16 + l16][quad * 8];
        #pragma unroll
        for (int i = 0; i < 4; i++)
            #pragma unroll
            for (int j = 0; j < 4; j++)
                acc[i][j] = __builtin_amdgcn_mfma_f32_16x16x32_bf16(
                    af[i], bfr[j], acc[i][j], 0, 0, 0);
        __syncthreads();
    }

    // epilogue: C/D layout col=lane&15, row=quad*4+reg (m89)
    #pragma unroll
    for (int i = 0; i < 4; i++) {
        #pragma unroll
        for (int rr = 0; rr < 4; rr++) {
            int row = m0 + wrow + i * 16 + quad * 4 + rr;
            if (row < M) {
                #pragma unroll
                for (int j = 0; j < 4; j++) {
                    int col = wcol + j * 16 + l16;
                    Cout[(size_t)row * DD + col] = f2bf(acc[i][j][rr] + bias[col]);
                }
            }
        }
    }
}

// ---------------- CSR build: histogram -> scan -> scatter(src/type) (once per call)
__global__ __launch_bounds__(256)
void hist_kernel(const int* __restrict__ ei, int* __restrict__ counts)
{
    int e = blockIdx.x * 256 + threadIdx.x;
    if (e < EE) atomicAdd(&counts[ei[EE + e]], 1);
}

#define SCAN_T 1024
__global__ __launch_bounds__(SCAN_T)
void scan_kernel(const int* __restrict__ counts, int* __restrict__ offsets)
{
    __shared__ int part[SCAN_T];
    int t = threadIdx.x;
    const int chunk = (NN + SCAN_T - 1) / SCAN_T;
    int b = t * chunk, e = min(b + chunk, NN);
    int mysum = 0;
    for (int i = b; i < e; i++) mysum += counts[i];
    part[t] = mysum;
    __syncthreads();
    for (int off = 1; off < SCAN_T; off <<= 1) {
        int v = (t >= off) ? part[t - off] : 0;
        __syncthreads();
        part[t] += v;
        __syncthreads();
    }
    int running = part[t] - mysum;
    for (int i = b; i < e; i++) { offsets[i] = running; running += counts[i]; }
    if (t == SCAN_T - 1) offsets[NN] = EE;
}

__global__ __launch_bounds__(256)
void scatter_kernel(const int* __restrict__ ei, const int* __restrict__ et,
                    const int* __restrict__ offsets,
                    int* __restrict__ fill, int* __restrict__ srcp,
                    int* __restrict__ typep)
{
    int e = blockIdx.x * 256 + threadIdx.x;
    if (e >= EE) return;
    int d = ei[EE + e];
    int pos = offsets[d] + atomicAdd(&fill[d], 1);
    srcp[pos]  = ei[e];
    typep[pos] = et[e];
}

// ---------------- fused: per-node logits + online softmax + aggregate + bias + act
// one wave per dst node; 4 nodes per 256-thread block; lane owns channels 2l,2l+1
__global__ __launch_bounds__(256)
void node_kernel(const int* __restrict__ srcp, const int* __restrict__ typep,
                 const int* __restrict__ offsets,
                 const u16* __restrict__ xl, const u16* __restrict__ xr,
                 const u16* __restrict__ erel, const float* __restrict__ att,
                 const float* __restrict__ bias,
                 u16* __restrict__ xnext, float* __restrict__ outp, int is_last)
{
    int tid = threadIdx.x;
    int node = blockIdx.x * 4 + (tid >> 6);
    int lane = tid & 63;
    if (node >= NN) return;
    int beg = offsets[node], end = offsets[node + 1];
    int ch = lane * 2;

    // per-node constants
    u32 xrp = *(const u32*)&xr[(size_t)node * DD + ch];
    float xr0 = bf2f((u16)xrp), xr1 = bf2f((u16)(xrp >> 16));
    float2 av = *(const float2*)&att[ch];

    // online-softmax state (replicated across each 16-lane head group)
    float m = -1e30f, s = 0.f, a0 = 0.f, a1 = 0.f;

    for (int cs = beg; cs < end; cs += 64) {
        int ccnt = min(64, end - cs);
        int slot = cs + lane;
        int src = (lane < ccnt) ? srcp[slot] : 0;
        int typ = (lane < ccnt) ? typep[slot] : 0;
        for (int i = 0; i < ccnt; i++) {
            int ss = __shfl(src, i, 64);
            int tt = __shfl(typ, i, 64);
            u32 xlp = *(const u32*)&xl[(size_t)ss * DD + ch];
            u32 erp = *(const u32*)&erel[(size_t)tt * DD + ch];
            float x0 = bf2f((u16)xlp), x1 = bf2f((u16)(xlp >> 16));
            float m0 = x0 + xr0 + bf2f((u16)erp);
            float m1 = x1 + xr1 + bf2f((u16)(erp >> 16));
            m0 = m0 > 0.f ? m0 : 0.2f * m0;   // leaky_relu BEFORE attention dot
            m1 = m1 > 0.f ? m1 : 0.2f * m1;
            float p = m0 * av.x + m1 * av.y;
            // head logit: reduce within the 16-lane group (head = lane>>4)
            p += __shfl_xor(p, 1, 64);
            p += __shfl_xor(p, 2, 64);
            p += __shfl_xor(p, 4, 64);
            p += __shfl_xor(p, 8, 64);
            // online softmax update
            float mn = fmaxf(m, p);
            float sc = __expf(m - mn);
            float w  = __expf(p - mn);
            s  = s * sc + w;
            a0 = a0 * sc + w * x0;
            a1 = a1 * sc + w * x1;
            m = mn;
        }
    }

    float rh = 1.f / fmaxf(s, 1e-30f);
    float v0 = a0 * rh + bias[ch], v1 = a1 * rh + bias[ch + 1];
    if (is_last) {
        outp[(size_t)node * DD + ch]     = v0;
        outp[(size_t)node * DD + ch + 1] = v1;
    } else {
        float w0 = v0 > 0.f ? v0 : __expf(v0) - 1.f;   // elu between layers
        float w1 = v1 > 0.f ? v1 : __expf(v1) - 1.f;
        u32 pk = (u32)f2bf(w0) | ((u32)f2bf(w1) << 16);
        *(u32*)&xnext[(size_t)node * DD + ch] = pk;
    }
}

extern "C" void kernel_launch(void* const* d_in, const int* in_sizes, int n_in,
                              void* d_out, int out_size, void* d_ws, size_t ws_size,
                              hipStream_t stream)
{
    const int*   entity        = (const int*)d_in[0];
    const int*   edge_index    = (const int*)d_in[1];
    const int*   edge_type     = (const int*)d_in[2];
    const float* node_features = (const float*)d_in[3];
    const float* rel_emb       = (const float*)d_in[4];
    const float* proj_w        = (const float*)d_in[5];
    const float* proj_b        = (const float*)d_in[6];
    const float* w_l           = (const float*)d_in[7];
    const float* b_l           = (const float*)d_in[8];
    const float* w_r           = (const float*)d_in[9];
    const float* b_r           = (const float*)d_in[10];
    const float* w_e           = (const float*)d_in[11];
    const float* att           = (const float*)d_in[12];
    const float* bias          = (const float*)d_in[13];

    // workspace (~32 MB):
    u16*   xb     = (u16*)d_ws;                            // NN*DD bf16 (layer input)
    u16*   xl     = xb + (size_t)NN * DD;                  // NN*DD bf16
    u16*   xr     = xl + (size_t)NN * DD;                  // NN*DD bf16
    u16*   erel   = xr + (size_t)NN * DD;                  // LL*RR*DD bf16
    int*   srcp   = (int*)(erel + (size_t)LL * RR * DD);   // EE int (src in dst-order)
    int*   typep  = srcp + (size_t)EE;                     // EE int
    int*   counts = typep + (size_t)EE;                    // NN int
    int*   fill   = counts + NN;                           // NN int
    int*   offsets= fill + NN;                             // NN+1 int

    // ---- CSR build (edges constant across layers: once per call)
    hipMemsetAsync(counts, 0, (size_t)NN * 2 * sizeof(int), stream);  // counts + fill
    hist_kernel<<<(EE + 255) / 256, 256, 0, stream>>>(edge_index, counts);
    scan_kernel<<<1, SCAN_T, 0, stream>>>(counts, offsets);
    scatter_kernel<<<(EE + 255) / 256, 256, 0, stream>>>(
        edge_index, edge_type, offsets, fill, srcp, typep);

    relproj_kernel<<<LL * RR, 128, 0, stream>>>(rel_emb, w_e, erel);

    const int GB = (NN + 127) / 128;
    gemm_mfma_kernel<false, true><<<GB, 256, 0, stream>>>(
        node_features, entity, FF, FF, proj_w, proj_b, xb, NN);

    for (int l = 0; l < LL; l++) {
        gemm_mfma_kernel<true, false><<<GB, 256, 0, stream>>>(
            xb, nullptr, DD, DD, w_l + (size_t)l * DD * DD, b_l + l * DD, xl, NN);
        gemm_mfma_kernel<true, false><<<GB, 256, 0, stream>>>(
            xb, nullptr, DD, DD, w_r + (size_t)l * DD * DD, b_r + l * DD, xr, NN);

        node_kernel<<<(NN + 3) / 4, 256, 0, stream>>>(
            srcp, typep, offsets, xl, xr, erel + (size_t)l * RR * DD,
            att + (size_t)l * DD, bias + (size_t)l * DD,
            xb, (float*)d_out, l == LL - 1);
    }
}

// Round 7
// 448.130 us; speedup vs baseline: 2.7279x; 1.1183x over previous
//
#include <hip/hip_runtime.h>

#define NN 50000
#define FF 300
#define DD 128
#define HH 4
#define CC 32
#define EE 640000
#define RR 200
#define LL 2

typedef unsigned short u16;
typedef unsigned int u32;
typedef unsigned long long u64;
typedef __attribute__((ext_vector_type(8))) short short8;   // 8 bf16 (4 VGPRs)
typedef __attribute__((ext_vector_type(4))) float floatx4;  // MFMA accumulator

__device__ __forceinline__ float bf2f(u16 u) {
    union { u32 i; float f; } v; v.i = ((u32)u) << 16; return v.f;
}
__device__ __forceinline__ u16 f2bf(float f) {
    u32 u = __float_as_uint(f);
    u32 r = (u >> 16) & 1u;
    u += 0x7fffu + r;
    return (u16)(u >> 16);
}
// unpack 2 bf16 from one u32 (lo, hi)
__device__ __forceinline__ void bf2x(u32 p, float& lo, float& hi) {
    lo = __uint_as_float(p << 16);
    hi = __uint_as_float(p & 0xffff0000u);
}

// ---------------- relation projection (bf16 out)
__global__ __launch_bounds__(128)
void relproj_kernel(const float* __restrict__ rel_emb,
                    const float* __restrict__ w_e,
                    u16* __restrict__ erel)
{
    int lr = blockIdx.x;            // l*RR + r
    int l = lr / RR, r = lr - l * RR;
    int d = threadIdx.x;
    __shared__ float rv[DD];
    rv[d] = rel_emb[r * DD + d];
    __syncthreads();
    const float* W = w_e + (size_t)l * DD * DD;
    float acc = 0.f;
    #pragma unroll 8
    for (int k = 0; k < DD; k++) acc += rv[k] * W[k * DD + d];
    erel[(size_t)lr * DD + d] = f2bf(acc);
}

// ---------------- MFMA bf16 GEMM: C[M,128] = A[M,K] @ B[K,128] + bias, out bf16
// blockIdx.y selects (B1,bias1,C1) or (B2,bias2,C2) — merges the l/r GEMMs.
template<bool ABF16, bool GATHER>
__global__ __launch_bounds__(256)
void gemm_mfma_kernel(const void* __restrict__ A_, const int* __restrict__ rowidx,
                      int lda, int K,
                      const float* __restrict__ B1, const float* __restrict__ bias1,
                      u16* __restrict__ C1,
                      const float* __restrict__ B2, const float* __restrict__ bias2,
                      u16* __restrict__ C2, int M)
{
    const float* B    = (blockIdx.y == 0) ? B1 : B2;
    const float* bias = (blockIdx.y == 0) ? bias1 : bias2;
    u16*         Cout = (blockIdx.y == 0) ? C1 : C2;

    __shared__ u16 As[128][40];
    __shared__ u16 Bs[128][40];   // Bs[n][k]
    int tid  = threadIdx.x;
    int m0   = blockIdx.x * 128;
    int wave = tid >> 6, lane = tid & 63;
    int quad = lane >> 4, l16 = lane & 15;
    int wrow = (wave >> 1) * 64, wcol = (wave & 1) * 64;

    floatx4 acc[4][4];
    #pragma unroll
    for (int i = 0; i < 4; i++)
        #pragma unroll
        for (int j = 0; j < 4; j++) acc[i][j] = (floatx4){0.f, 0.f, 0.f, 0.f};

    int ar = tid >> 1, ahalf = tid & 1;
    int arow = m0 + ar;
    int rid = (arow < M) ? (GATHER ? rowidx[arow] : arow) : 0;
    int bk = tid >> 3, bn0 = (tid & 7) * 16;

    for (int kk = 0; kk < K; kk += 32) {
        {
            int kb = kk + ahalf * 16;
            u16 tmp[16];
            if (ABF16) {
                const u16* Ap = (const u16*)A_ + (size_t)rid * lda + kb;
                if (kb + 16 <= K) {
                    *(short8*)&tmp[0] = *(const short8*)Ap;
                    *(short8*)&tmp[8] = *(const short8*)(Ap + 8);
                } else {
                    #pragma unroll
                    for (int j = 0; j < 16; j++) tmp[j] = (kb + j < K) ? Ap[j] : (u16)0;
                }
            } else {
                const float* Ap = (const float*)A_ + (size_t)rid * lda + kb;
                if (kb + 16 <= K) {
                    #pragma unroll
                    for (int q = 0; q < 4; q++) {
                        float4 f = *(const float4*)(Ap + q * 4);
                        tmp[q*4+0] = f2bf(f.x); tmp[q*4+1] = f2bf(f.y);
                        tmp[q*4+2] = f2bf(f.z); tmp[q*4+3] = f2bf(f.w);
                    }
                } else {
                    #pragma unroll
                    for (int j = 0; j < 16; j++) tmp[j] = (kb + j < K) ? f2bf(Ap[j]) : (u16)0;
                }
            }
            *(short8*)&As[ar][ahalf * 16]     = *(short8*)&tmp[0];
            *(short8*)&As[ar][ahalf * 16 + 8] = *(short8*)&tmp[8];
        }
        {
            int k = kk + bk;
            float vals[16];
            if (k < K) {
                const float* Bp = B + (size_t)k * DD + bn0;
                #pragma unroll
                for (int q = 0; q < 4; q++) {
                    float4 f = *(const float4*)(Bp + q * 4);
                    vals[q*4+0] = f.x; vals[q*4+1] = f.y;
                    vals[q*4+2] = f.z; vals[q*4+3] = f.w;
                }
            } else {
                #pragma unroll
                for (int j = 0; j < 16; j++) vals[j] = 0.f;
            }
            #pragma unroll
            for (int j = 0; j < 16; j++) Bs[bn0 + j][bk] = f2bf(vals[j]);
        }
        __syncthreads();
        short8 af[4], bfr[4];
        #pragma unroll
        for (int i = 0; i < 4; i++)
            af[i] = *(const short8*)&As[wrow + i * 16 + l16][quad * 8];
        #pragma unroll
        for (int j = 0; j < 4; j++)
            bfr[j] = *(const short8*)&Bs[wcol + j * 16 + l16][quad * 8];
        #pragma unroll
        for (int i = 0; i < 4; i++)
            #pragma unroll
            for (int j = 0; j < 4; j++)
                acc[i][j] = __builtin_amdgcn_mfma_f32_16x16x32_bf16(
                    af[i], bfr[j], acc[i][j], 0, 0, 0);
        __syncthreads();
    }

    // epilogue: C/D layout col=lane&15, row=quad*4+reg (m89)
    #pragma unroll
    for (int i = 0; i < 4; i++) {
        #pragma unroll
        for (int rr = 0; rr < 4; rr++) {
            int row = m0 + wrow + i * 16 + quad * 4 + rr;
            if (row < M) {
                #pragma unroll
                for (int j = 0; j < 4; j++) {
                    int col = wcol + j * 16 + l16;
                    Cout[(size_t)row * DD + col] = f2bf(acc[i][j][rr] + bias[col]);
                }
            }
        }
    }
}

// ---------------- CSR build: histogram -> scan -> scatter(src/type)
__global__ __launch_bounds__(256)
void hist_kernel(const int* __restrict__ ei, int* __restrict__ counts)
{
    int e = blockIdx.x * 256 + threadIdx.x;
    if (e < EE) atomicAdd(&counts[ei[EE + e]], 1);
}

#define SCAN_T 1024
__global__ __launch_bounds__(SCAN_T)
void scan_kernel(const int* __restrict__ counts, int* __restrict__ offsets)
{
    __shared__ int part[SCAN_T];
    int t = threadIdx.x;
    const int chunk = (NN + SCAN_T - 1) / SCAN_T;
    int b = t * chunk, e = min(b + chunk, NN);
    int mysum = 0;
    for (int i = b; i < e; i++) mysum += counts[i];
    part[t] = mysum;
    __syncthreads();
    for (int off = 1; off < SCAN_T; off <<= 1) {
        int v = (t >= off) ? part[t - off] : 0;
        __syncthreads();
        part[t] += v;
        __syncthreads();
    }
    int running = part[t] - mysum;
    for (int i = b; i < e; i++) { offsets[i] = running; running += counts[i]; }
    if (t == SCAN_T - 1) offsets[NN] = EE;
}

__global__ __launch_bounds__(256)
void scatter_kernel(const int* __restrict__ ei, const int* __restrict__ et,
                    const int* __restrict__ offsets,
                    int* __restrict__ fill, int* __restrict__ srcp,
                    int* __restrict__ typep)
{
    int e = blockIdx.x * 256 + threadIdx.x;
    if (e >= EE) return;
    int d = ei[EE + e];
    int pos = offsets[d] + atomicAdd(&fill[d], 1);
    srcp[pos]  = ei[e];
    typep[pos] = et[e];
}

// ---------------- fused per-node: logits + softmax (no-shift) + aggregate + bias + act
// one wave per dst node; 4 edge-groups of 16 lanes; lane owns 8 channels (ch = (lane&15)*8)
__global__ __launch_bounds__(256)
void node_kernel(const int* __restrict__ srcp, const int* __restrict__ typep,
                 const int* __restrict__ offsets,
                 const u16* __restrict__ xl, const u16* __restrict__ xr,
                 const u16* __restrict__ erel, const float* __restrict__ att,
                 const float* __restrict__ bias,
                 u16* __restrict__ xnext, float* __restrict__ outp, int is_last)
{
    int tid  = threadIdx.x;
    int node = blockIdx.x * 4 + (tid >> 6);
    int lane = tid & 63;
    if (node >= NN) return;
    int g  = lane >> 4;          // edge slot within quad
    int gl = lane & 15;          // channel set
    int c0 = gl * 8;
    int beg = offsets[node], end = offsets[node + 1];

    // per-node constants: xr channels + att channels (registers)
    float xrf[8], attf[8];
    {
        const u32* xp = (const u32*)&xr[(size_t)node * DD + c0];
        #pragma unroll
        for (int q = 0; q < 4; q++) bf2x(xp[q], xrf[q*2], xrf[q*2+1]);
        float4 a0 = *(const float4*)&att[c0];
        float4 a1 = *(const float4*)&att[c0 + 4];
        attf[0]=a0.x; attf[1]=a0.y; attf[2]=a0.z; attf[3]=a0.w;
        attf[4]=a1.x; attf[5]=a1.y; attf[6]=a1.z; attf[7]=a1.w;
    }

    float s = 0.f;
    float a[8];
    #pragma unroll
    for (int j = 0; j < 8; j++) a[j] = 0.f;

    for (int base = beg; base < end; base += 4) {
        int es = base + g;
        bool valid = es < end;
        int src = valid ? srcp[es] : 0;
        int typ = valid ? typep[es] : 0;
        const u32* xp = (const u32*)&xl[(size_t)src * DD + c0];
        const u32* ep = (const u32*)&erel[(size_t)typ * DD + c0];
        u32 xv0 = xp[0], xv1 = xp[1], xv2 = xp[2], xv3 = xp[3];
        u32 ev0 = ep[0], ev1 = ep[1], ev2 = ep[2], ev3 = ep[3];
        float xf[8], ef[8];
        bf2x(xv0, xf[0], xf[1]); bf2x(xv1, xf[2], xf[3]);
        bf2x(xv2, xf[4], xf[5]); bf2x(xv3, xf[6], xf[7]);
        bf2x(ev0, ef[0], ef[1]); bf2x(ev1, ef[2], ef[3]);
        bf2x(ev2, ef[4], ef[5]); bf2x(ev3, ef[6], ef[7]);
        float p = 0.f;
        #pragma unroll
        for (int j = 0; j < 8; j++) {
            float m = xf[j] + xrf[j] + ef[j];
            m = fmaxf(m, 0.2f * m);         // leaky_relu (slope<1): max(x, 0.2x)
            p += m * attf[j];
        }
        // per-head logit: reduce over the 4 lanes of this head (gl span of 4)
        p += __shfl_xor(p, 1, 64);
        p += __shfl_xor(p, 2, 64);
        // softmax without max-shift: logits are O(1); clamp guards inf
        float w = valid ? __expf(fminf(p, 60.f)) : 0.f;
        s += w;
        #pragma unroll
        for (int j = 0; j < 8; j++) a[j] += w * xf[j];
    }

    // cross-group reduction (groups processed disjoint edges)
    #pragma unroll
    for (int j = 0; j < 8; j++) {
        a[j] += __shfl_xor(a[j], 16, 64);
        a[j] += __shfl_xor(a[j], 32, 64);
    }
    s += __shfl_xor(s, 16, 64);
    s += __shfl_xor(s, 32, 64);

    if (lane < 16) {
        float rh = 1.f / fmaxf(s, 1e-30f);
        float4 b0 = *(const float4*)&bias[c0];
        float4 b1 = *(const float4*)&bias[c0 + 4];
        float bv[8] = {b0.x, b0.y, b0.z, b0.w, b1.x, b1.y, b1.z, b1.w};
        float v[8];
        #pragma unroll
        for (int j = 0; j < 8; j++) v[j] = a[j] * rh + bv[j];
        if (is_last) {
            float4* op = (float4*)&outp[(size_t)node * DD + c0];
            op[0] = make_float4(v[0], v[1], v[2], v[3]);
            op[1] = make_float4(v[4], v[5], v[6], v[7]);
        } else {
            u16 pk[8];
            #pragma unroll
            for (int j = 0; j < 8; j++) {
                float w2 = v[j] > 0.f ? v[j] : __expf(v[j]) - 1.f;   // elu
                pk[j] = f2bf(w2);
            }
            *(short8*)&xnext[(size_t)node * DD + c0] = *(short8*)pk;
        }
    }
}

extern "C" void kernel_launch(void* const* d_in, const int* in_sizes, int n_in,
                              void* d_out, int out_size, void* d_ws, size_t ws_size,
                              hipStream_t stream)
{
    const int*   entity        = (const int*)d_in[0];
    const int*   edge_index    = (const int*)d_in[1];
    const int*   edge_type     = (const int*)d_in[2];
    const float* node_features = (const float*)d_in[3];
    const float* rel_emb       = (const float*)d_in[4];
    const float* proj_w        = (const float*)d_in[5];
    const float* proj_b        = (const float*)d_in[6];
    const float* w_l           = (const float*)d_in[7];
    const float* b_l           = (const float*)d_in[8];
    const float* w_r           = (const float*)d_in[9];
    const float* b_r           = (const float*)d_in[10];
    const float* w_e           = (const float*)d_in[11];
    const float* att           = (const float*)d_in[12];
    const float* bias          = (const float*)d_in[13];

    // workspace (~32 MB):
    u16*   xb     = (u16*)d_ws;                            // NN*DD bf16 (layer input)
    u16*   xl     = xb + (size_t)NN * DD;                  // NN*DD bf16
    u16*   xr     = xl + (size_t)NN * DD;                  // NN*DD bf16
    u16*   erel   = xr + (size_t)NN * DD;                  // LL*RR*DD bf16
    int*   srcp   = (int*)(erel + (size_t)LL * RR * DD);   // EE int (src in dst-order)
    int*   typep  = srcp + (size_t)EE;                     // EE int
    int*   counts = typep + (size_t)EE;                    // NN int
    int*   fill   = counts + NN;                           // NN int
    int*   offsets= fill + NN;                             // NN+1 int

    // ---- CSR build (edges constant across layers: once per call)
    hipMemsetAsync(counts, 0, (size_t)NN * 2 * sizeof(int), stream);  // counts + fill
    hist_kernel<<<(EE + 255) / 256, 256, 0, stream>>>(edge_index, counts);
    scan_kernel<<<1, SCAN_T, 0, stream>>>(counts, offsets);
    scatter_kernel<<<(EE + 255) / 256, 256, 0, stream>>>(
        edge_index, edge_type, offsets, fill, srcp, typep);

    relproj_kernel<<<LL * RR, 128, 0, stream>>>(rel_emb, w_e, erel);

    const int GB = (NN + 127) / 128;
    gemm_mfma_kernel<false, true><<<dim3(GB, 1), 256, 0, stream>>>(
        node_features, entity, FF, FF, proj_w, proj_b, xb,
        proj_w, proj_b, xb, NN);

    for (int l = 0; l < LL; l++) {
        // w_l and w_r in one dispatch (gridDim.y = 2)
        gemm_mfma_kernel<true, false><<<dim3(GB, 2), 256, 0, stream>>>(
            xb, nullptr, DD, DD,
            w_l + (size_t)l * DD * DD, b_l + l * DD, xl,
            w_r + (size_t)l * DD * DD, b_r + l * DD, xr, NN);

        node_kernel<<<(NN + 3) / 4, 256, 0, stream>>>(
            srcp, typep, offsets, xl, xr, erel + (size_t)l * RR * DD,
            att + (size_t)l * DD, bias + (size_t)l * DD,
            xb, (float*)d_out, l == LL - 1);
    }
}

// Round 8
// 380.842 us; speedup vs baseline: 3.2098x; 1.1767x over previous
//
#include <hip/hip_runtime.h>

#define NN 50000
#define FF 300
#define DD 128
#define HH 4
#define CC 32
#define EE 640000
#define RR 200
#define LL 2
#define SB ((NN + 255) / 256)   // scan blocks = 196

typedef unsigned short u16;
typedef unsigned int u32;
typedef unsigned long long u64;
typedef __attribute__((ext_vector_type(8))) short short8;   // 8 bf16 (4 VGPRs)
typedef __attribute__((ext_vector_type(4))) float floatx4;  // MFMA accumulator

__device__ __forceinline__ float bf2f(u16 u) {
    union { u32 i; float f; } v; v.i = ((u32)u) << 16; return v.f;
}
__device__ __forceinline__ u16 f2bf(float f) {
    u32 u = __float_as_uint(f);
    u32 r = (u >> 16) & 1u;
    u += 0x7fffu + r;
    return (u16)(u >> 16);
}
// unpack 2 bf16 from one u32 (lo, hi)
__device__ __forceinline__ void bf2x(u32 p, float& lo, float& hi) {
    lo = __uint_as_float(p << 16);
    hi = __uint_as_float(p & 0xffff0000u);
}

// block-wide (256 threads) scan: returns exclusive prefix of v; *total = block sum
__device__ __forceinline__ int block_excl_scan(int v, int* lds4, int* total) {
    int lane = threadIdx.x & 63, wid = threadIdx.x >> 6;
    int x = v;
    #pragma unroll
    for (int off = 1; off < 64; off <<= 1) {
        int y = __shfl_up(x, off, 64);
        if (lane >= off) x += y;
    }
    if (lane == 63) lds4[wid] = x;
    __syncthreads();
    int add = 0;
    #pragma unroll
    for (int w = 0; w < 4; w++) add += (w < wid) ? lds4[w] : 0;
    *total = lds4[0] + lds4[1] + lds4[2] + lds4[3];
    return x + add - v;
}

// ---------------- relation projection (bf16 out)
__global__ __launch_bounds__(128)
void relproj_kernel(const float* __restrict__ rel_emb,
                    const float* __restrict__ w_e,
                    u16* __restrict__ erel)
{
    int lr = blockIdx.x;            // l*RR + r
    int l = lr / RR, r = lr - l * RR;
    int d = threadIdx.x;
    __shared__ float rv[DD];
    rv[d] = rel_emb[r * DD + d];
    __syncthreads();
    const float* W = w_e + (size_t)l * DD * DD;
    float acc = 0.f;
    #pragma unroll 8
    for (int k = 0; k < DD; k++) acc += rv[k] * W[k * DD + d];
    erel[(size_t)lr * DD + d] = f2bf(acc);
}

// ---------------- MFMA bf16 GEMM: C[M,128] = A[M,K] @ B[K,128] + bias, out bf16
// blockIdx.y selects (B1,bias1,C1) or (B2,bias2,C2) — merges the l/r GEMMs.
template<bool ABF16, bool GATHER>
__global__ __launch_bounds__(256)
void gemm_mfma_kernel(const void* __restrict__ A_, const int* __restrict__ rowidx,
                      int lda, int K,
                      const float* __restrict__ B1, const float* __restrict__ bias1,
                      u16* __restrict__ C1,
                      const float* __restrict__ B2, const float* __restrict__ bias2,
                      u16* __restrict__ C2, int M)
{
    const float* B    = (blockIdx.y == 0) ? B1 : B2;
    const float* bias = (blockIdx.y == 0) ? bias1 : bias2;
    u16*         Cout = (blockIdx.y == 0) ? C1 : C2;

    __shared__ u16 As[128][40];
    __shared__ u16 Bs[128][40];   // Bs[n][k]
    int tid  = threadIdx.x;
    int m0   = blockIdx.x * 128;
    int wave = tid >> 6, lane = tid & 63;
    int quad = lane >> 4, l16 = lane & 15;
    int wrow = (wave >> 1) * 64, wcol = (wave & 1) * 64;

    floatx4 acc[4][4];
    #pragma unroll
    for (int i = 0; i < 4; i++)
        #pragma unroll
        for (int j = 0; j < 4; j++) acc[i][j] = (floatx4){0.f, 0.f, 0.f, 0.f};

    int ar = tid >> 1, ahalf = tid & 1;
    int arow = m0 + ar;
    int rid = (arow < M) ? (GATHER ? rowidx[arow] : arow) : 0;
    int bk = tid >> 3, bn0 = (tid & 7) * 16;

    for (int kk = 0; kk < K; kk += 32) {
        {
            int kb = kk + ahalf * 16;
            u16 tmp[16];
            if (ABF16) {
                const u16* Ap = (const u16*)A_ + (size_t)rid * lda + kb;
                if (kb + 16 <= K) {
                    *(short8*)&tmp[0] = *(const short8*)Ap;
                    *(short8*)&tmp[8] = *(const short8*)(Ap + 8);
                } else {
                    #pragma unroll
                    for (int j = 0; j < 16; j++) tmp[j] = (kb + j < K) ? Ap[j] : (u16)0;
                }
            } else {
                const float* Ap = (const float*)A_ + (size_t)rid * lda + kb;
                if (kb + 16 <= K) {
                    #pragma unroll
                    for (int q = 0; q < 4; q++) {
                        float4 f = *(const float4*)(Ap + q * 4);
                        tmp[q*4+0] = f2bf(f.x); tmp[q*4+1] = f2bf(f.y);
                        tmp[q*4+2] = f2bf(f.z); tmp[q*4+3] = f2bf(f.w);
                    }
                } else {
                    #pragma unroll
                    for (int j = 0; j < 16; j++) tmp[j] = (kb + j < K) ? f2bf(Ap[j]) : (u16)0;
                }
            }
            *(short8*)&As[ar][ahalf * 16]     = *(short8*)&tmp[0];
            *(short8*)&As[ar][ahalf * 16 + 8] = *(short8*)&tmp[8];
        }
        {
            int k = kk + bk;
            float vals[16];
            if (k < K) {
                const float* Bp = B + (size_t)k * DD + bn0;
                #pragma unroll
                for (int q = 0; q < 4; q++) {
                    float4 f = *(const float4*)(Bp + q * 4);
                    vals[q*4+0] = f.x; vals[q*4+1] = f.y;
                    vals[q*4+2] = f.z; vals[q*4+3] = f.w;
                }
            } else {
                #pragma unroll
                for (int j = 0; j < 16; j++) vals[j] = 0.f;
            }
            #pragma unroll
            for (int j = 0; j < 16; j++) Bs[bn0 + j][bk] = f2bf(vals[j]);
        }
        __syncthreads();
        short8 af[4], bfr[4];
        #pragma unroll
        for (int i = 0; i < 4; i++)
            af[i] = *(const short8*)&As[wrow + i * 16 + l16][quad * 8];
        #pragma unroll
        for (int j = 0; j < 4; j++)
            bfr[j] = *(const short8*)&Bs[wcol + j * 16 + l16][quad * 8];
        #pragma unroll
        for (int i = 0; i < 4; i++)
            #pragma unroll
            for (int j = 0; j < 4; j++)
                acc[i][j] = __builtin_amdgcn_mfma_f32_16x16x32_bf16(
                    af[i], bfr[j], acc[i][j], 0, 0, 0);
        __syncthreads();
    }

    // epilogue: C/D layout col=lane&15, row=quad*4+reg (m89)
    #pragma unroll
    for (int i = 0; i < 4; i++) {
        #pragma unroll
        for (int rr = 0; rr < 4; rr++) {
            int row = m0 + wrow + i * 16 + quad * 4 + rr;
            if (row < M) {
                #pragma unroll
                for (int j = 0; j < 4; j++) {
                    int col = wcol + j * 16 + l16;
                    Cout[(size_t)row * DD + col] = f2bf(acc[i][j][rr] + bias[col]);
                }
            }
        }
    }
}

// ---------------- CSR build: histogram -> hierarchical scan -> scatter
__global__ __launch_bounds__(256)
void hist_kernel(const int* __restrict__ ei, int* __restrict__ counts)
{
    int e = blockIdx.x * 256 + threadIdx.x;
    if (e < EE) atomicAdd(&counts[ei[EE + e]], 1);
}

__global__ __launch_bounds__(256)
void scan_local_kernel(const int* __restrict__ counts, int* __restrict__ offsets,
                       int* __restrict__ bsum)
{
    __shared__ int lds4[4];
    int i = blockIdx.x * 256 + threadIdx.x;
    int v = (i < NN) ? counts[i] : 0;
    int total;
    int ex = block_excl_scan(v, lds4, &total);
    if (i < NN) offsets[i] = ex;
    if (threadIdx.x == 0) bsum[blockIdx.x] = total;
}

__global__ __launch_bounds__(256)
void scan_bsum_kernel(int* __restrict__ bsum)
{
    __shared__ int lds4[4];
    int t = threadIdx.x;
    int v = (t < SB) ? bsum[t] : 0;
    int total;
    int ex = block_excl_scan(v, lds4, &total);
    if (t < SB) bsum[t] = ex;
}

__global__ __launch_bounds__(256)
void scan_add_kernel(int* __restrict__ offsets, const int* __restrict__ bsum)
{
    int i = blockIdx.x * 256 + threadIdx.x;
    if (i < NN) offsets[i] += bsum[i >> 8];
    if (i == 0) offsets[NN] = EE;
}

__global__ __launch_bounds__(256)
void scatter_kernel(const int* __restrict__ ei, const int* __restrict__ et,
                    const int* __restrict__ offsets,
                    int* __restrict__ fill, int* __restrict__ srcp,
                    int* __restrict__ typep)
{
    int e = blockIdx.x * 256 + threadIdx.x;
    if (e >= EE) return;
    int d = ei[EE + e];
    int pos = offsets[d] + atomicAdd(&fill[d], 1);
    srcp[pos]  = ei[e];
    typep[pos] = et[e];
}

// ---------------- fused per-node: logits + softmax (no-shift) + aggregate + bias + act
// one wave per dst node; 4 edge-groups of 16 lanes; lane owns 8 channels (ch = (lane&15)*8)
__global__ __launch_bounds__(256)
void node_kernel(const int* __restrict__ srcp, const int* __restrict__ typep,
                 const int* __restrict__ offsets,
                 const u16* __restrict__ xl, const u16* __restrict__ xr,
                 const u16* __restrict__ erel, const float* __restrict__ att,
                 const float* __restrict__ bias,
                 u16* __restrict__ xnext, float* __restrict__ outp, int is_last)
{
    int tid  = threadIdx.x;
    int node = blockIdx.x * 4 + (tid >> 6);
    int lane = tid & 63;
    if (node >= NN) return;
    int g  = lane >> 4;          // edge slot within quad
    int gl = lane & 15;          // channel set
    int c0 = gl * 8;
    int beg = offsets[node], end = offsets[node + 1];

    // per-node constants: xr channels + att channels (registers)
    float xrf[8], attf[8];
    {
        const u32* xp = (const u32*)&xr[(size_t)node * DD + c0];
        #pragma unroll
        for (int q = 0; q < 4; q++) bf2x(xp[q], xrf[q*2], xrf[q*2+1]);
        float4 a0 = *(const float4*)&att[c0];
        float4 a1 = *(const float4*)&att[c0 + 4];
        attf[0]=a0.x; attf[1]=a0.y; attf[2]=a0.z; attf[3]=a0.w;
        attf[4]=a1.x; attf[5]=a1.y; attf[6]=a1.z; attf[7]=a1.w;
    }

    float s = 0.f;
    float a[8];
    #pragma unroll
    for (int j = 0; j < 8; j++) a[j] = 0.f;

    for (int base = beg; base < end; base += 4) {
        int es = base + g;
        bool valid = es < end;
        int src = valid ? srcp[es] : 0;
        int typ = valid ? typep[es] : 0;
        const u32* xp = (const u32*)&xl[(size_t)src * DD + c0];
        const u32* ep = (const u32*)&erel[(size_t)typ * DD + c0];
        u32 xv0 = xp[0], xv1 = xp[1], xv2 = xp[2], xv3 = xp[3];
        u32 ev0 = ep[0], ev1 = ep[1], ev2 = ep[2], ev3 = ep[3];
        float xf[8], ef[8];
        bf2x(xv0, xf[0], xf[1]); bf2x(xv1, xf[2], xf[3]);
        bf2x(xv2, xf[4], xf[5]); bf2x(xv3, xf[6], xf[7]);
        bf2x(ev0, ef[0], ef[1]); bf2x(ev1, ef[2], ef[3]);
        bf2x(ev2, ef[4], ef[5]); bf2x(ev3, ef[6], ef[7]);
        float p = 0.f;
        #pragma unroll
        for (int j = 0; j < 8; j++) {
            float m = xf[j] + xrf[j] + ef[j];
            m = fmaxf(m, 0.2f * m);         // leaky_relu (slope<1): max(x, 0.2x)
            p += m * attf[j];
        }
        // per-head logit: reduce over the 4 lanes of this head (gl span of 4)
        p += __shfl_xor(p, 1, 64);
        p += __shfl_xor(p, 2, 64);
        // softmax without max-shift: logits are O(1); clamp guards inf
        float w = valid ? __expf(fminf(p, 60.f)) : 0.f;
        s += w;
        #pragma unroll
        for (int j = 0; j < 8; j++) a[j] += w * xf[j];
    }

    // cross-group reduction (groups processed disjoint edges)
    #pragma unroll
    for (int j = 0; j < 8; j++) {
        a[j] += __shfl_xor(a[j], 16, 64);
        a[j] += __shfl_xor(a[j], 32, 64);
    }
    s += __shfl_xor(s, 16, 64);
    s += __shfl_xor(s, 32, 64);

    if (lane < 16) {
        float rh = 1.f / fmaxf(s, 1e-30f);
        float4 b0 = *(const float4*)&bias[c0];
        float4 b1 = *(const float4*)&bias[c0 + 4];
        float bv[8] = {b0.x, b0.y, b0.z, b0.w, b1.x, b1.y, b1.z, b1.w};
        float v[8];
        #pragma unroll
        for (int j = 0; j < 8; j++) v[j] = a[j] * rh + bv[j];
        if (is_last) {
            float4* op = (float4*)&outp[(size_t)node * DD + c0];
            op[0] = make_float4(v[0], v[1], v[2], v[3]);
            op[1] = make_float4(v[4], v[5], v[6], v[7]);
        } else {
            u16 pk[8];
            #pragma unroll
            for (int j = 0; j < 8; j++) {
                float w2 = v[j] > 0.f ? v[j] : __expf(v[j]) - 1.f;   // elu
                pk[j] = f2bf(w2);
            }
            *(short8*)&xnext[(size_t)node * DD + c0] = *(short8*)pk;
        }
    }
}

extern "C" void kernel_launch(void* const* d_in, const int* in_sizes, int n_in,
                              void* d_out, int out_size, void* d_ws, size_t ws_size,
                              hipStream_t stream)
{
    const int*   entity        = (const int*)d_in[0];
    const int*   edge_index    = (const int*)d_in[1];
    const int*   edge_type     = (const int*)d_in[2];
    const float* node_features = (const float*)d_in[3];
    const float* rel_emb       = (const float*)d_in[4];
    const float* proj_w        = (const float*)d_in[5];
    const float* proj_b        = (const float*)d_in[6];
    const float* w_l           = (const float*)d_in[7];
    const float* b_l           = (const float*)d_in[8];
    const float* w_r           = (const float*)d_in[9];
    const float* b_r           = (const float*)d_in[10];
    const float* w_e           = (const float*)d_in[11];
    const float* att           = (const float*)d_in[12];
    const float* bias          = (const float*)d_in[13];

    // workspace (~32 MB):
    u16*   xb     = (u16*)d_ws;                            // NN*DD bf16 (layer input)
    u16*   xl     = xb + (size_t)NN * DD;                  // NN*DD bf16
    u16*   xr     = xl + (size_t)NN * DD;                  // NN*DD bf16
    u16*   erel   = xr + (size_t)NN * DD;                  // LL*RR*DD bf16
    int*   srcp   = (int*)(erel + (size_t)LL * RR * DD);   // EE int (src in dst-order)
    int*   typep  = srcp + (size_t)EE;                     // EE int
    int*   counts = typep + (size_t)EE;                    // NN int
    int*   fill   = counts + NN;                           // NN int
    int*   offsets= fill + NN;                             // NN+1 int
    int*   bsum   = offsets + NN + 1;                      // SB int

    // ---- CSR build (edges constant across layers: once per call)
    hipMemsetAsync(counts, 0, (size_t)NN * 2 * sizeof(int), stream);  // counts + fill
    hist_kernel<<<(EE + 255) / 256, 256, 0, stream>>>(edge_index, counts);
    scan_local_kernel<<<SB, 256, 0, stream>>>(counts, offsets, bsum);
    scan_bsum_kernel<<<1, 256, 0, stream>>>(bsum);
    scan_add_kernel<<<SB, 256, 0, stream>>>(offsets, bsum);
    scatter_kernel<<<(EE + 255) / 256, 256, 0, stream>>>(
        edge_index, edge_type, offsets, fill, srcp, typep);

    relproj_kernel<<<LL * RR, 128, 0, stream>>>(rel_emb, w_e, erel);

    const int GB = (NN + 127) / 128;
    gemm_mfma_kernel<false, true><<<dim3(GB, 1), 256, 0, stream>>>(
        node_features, entity, FF, FF, proj_w, proj_b, xb,
        proj_w, proj_b, xb, NN);

    for (int l = 0; l < LL; l++) {
        // w_l and w_r in one dispatch (gridDim.y = 2)
        gemm_mfma_kernel<true, false><<<dim3(GB, 2), 256, 0, stream>>>(
            xb, nullptr, DD, DD,
            w_l + (size_t)l * DD * DD, b_l + l * DD, xl,
            w_r + (size_t)l * DD * DD, b_r + l * DD, xr, NN);

        node_kernel<<<(NN + 3) / 4, 256, 0, stream>>>(
            srcp, typep, offsets, xl, xr, erel + (size_t)l * RR * DD,
            att + (size_t)l * DD, bias + (size_t)l * DD,
            xb, (float*)d_out, l == LL - 1);
    }
}